// Round 1
// baseline (3295.458 us; speedup 1.0000x reference)
//
#include <hip/hip_runtime.h>

// TGCN forward, algebraically reduced (H0 = 0 => R/Wr dead, Z*H = 0):
//   deg[d] = #edges into d ; dinv = rsqrt(deg+1)
//   agg[n] = sum_{e: dst=n} x[src]*dinv[src]*dinv[dst]  + x[n]*dinv[n]^2
//   Mz = Wz @ Lzw[0:256], cz = bz @ Lzw[0:256] + Lzb   (same for h)
//   Z = sigmoid(agg@Mz + cz), Ht = tanh(agg@Mh + ch)
//   h = relu((1-Z)*Ht) ; out = softmax(h @ Wo + bo)

__global__ __launch_bounds__(256) void deg_kernel(const int* __restrict__ dsts,
                                                  float* __restrict__ deg, int E) {
    int e = blockIdx.x * 256 + threadIdx.x;
    if (e < E) atomicAdd(&deg[dsts[e]], 1.0f);
}

__global__ __launch_bounds__(256) void dinv_kernel(const float* __restrict__ deg,
                                                   float* __restrict__ dinv, int n) {
    int i = blockIdx.x * 256 + threadIdx.x;
    if (i < n) dinv[i] = rsqrtf(deg[i] + 1.0f);
}

// one float4 of channels per thread: 16 threads/edge, coalesced x read,
// 4 fp32 atomics into agg[dst]
__global__ __launch_bounds__(256) void edge_agg_kernel(const int* __restrict__ srcs,
                                                       const int* __restrict__ dsts,
                                                       const float* __restrict__ x,
                                                       const float* __restrict__ dinv,
                                                       float* __restrict__ agg, int E) {
    int idx = blockIdx.x * 256 + threadIdx.x;   // over E*16
    int e = idx >> 4;
    int c = idx & 15;
    if (e >= E) return;
    int s = srcs[e], d = dsts[e];
    float nrm = dinv[s] * dinv[d];
    float4 v = ((const float4*)x)[s * 16 + c];
    float* ap = agg + (size_t)d * 64 + (size_t)c * 4;
    atomicAdd(ap + 0, v.x * nrm);
    atomicAdd(ap + 1, v.y * nrm);
    atomicAdd(ap + 2, v.z * nrm);
    atomicAdd(ap + 3, v.w * nrm);
}

// Mz[k][j] = sum_t W[k][t] * L[t][j]   (k<64);  row k==64 computes the bias fold
__global__ __launch_bounds__(256) void build_m_kernel(
    const float* __restrict__ Wz, const float* __restrict__ bz,
    const float* __restrict__ Wh, const float* __restrict__ bh,
    const float* __restrict__ Lzw, const float* __restrict__ Lzb,
    const float* __restrict__ Lhw, const float* __restrict__ Lhb,
    float* __restrict__ Mz, float* __restrict__ cz,
    float* __restrict__ Mh, float* __restrict__ ch) {
    int j = threadIdx.x;
    int k = blockIdx.x;          // 0..64 (64 == bias row)
    int which = blockIdx.y;      // 0=z, 1=h
    const float* W  = which ? Wh  : Wz;
    const float* bv = which ? bh  : bz;
    const float* L  = which ? Lhw : Lzw;   // [512,256]; only rows 0..255 matter (H0=0)
    const float* Lb = which ? Lhb : Lzb;
    float* M  = which ? Mh : Mz;
    float* cv = which ? ch : cz;
    float acc = 0.f;
    if (k < 64) {
        for (int t = 0; t < 256; ++t) acc = fmaf(W[k * 256 + t], L[t * 256 + j], acc);
        M[k * 256 + j] = acc;
    } else {
        for (int t = 0; t < 256; ++t) acc = fmaf(bv[t], L[t * 256 + j], acc);
        cv[j] = acc + Lb[j];
    }
}

// one block per node-slice; thread j owns output channel j; M columns live in
// 128 VGPRs, agg row broadcast from LDS via float4 reads
__global__ __launch_bounds__(256) void node_kernel(
    const float* __restrict__ agg, const float* __restrict__ x,
    const float* __restrict__ dinv,
    const float* __restrict__ Mz, const float* __restrict__ cz,
    const float* __restrict__ Mh, const float* __restrict__ ch,
    const float* __restrict__ Wo, const float* __restrict__ bo,
    float* __restrict__ out, int n) {
    int tid = threadIdx.x;
    float mz[64], mh[64];
#pragma unroll
    for (int k = 0; k < 64; ++k) {
        mz[k] = Mz[k * 256 + tid];
        mh[k] = Mh[k * 256 + tid];
    }
    float czj = cz[tid], chj = ch[tid];
    float4 wo = ((const float4*)Wo)[tid];   // Wo row tid: [256,4] row-major
    float bo0 = bo[0], bo1 = bo[1], bo2 = bo[2], bo3 = bo[3];
    __shared__ __align__(16) float sA[64];
    __shared__ float sRed[16];
    for (int node = blockIdx.x; node < n; node += gridDim.x) {
        float di = dinv[node];
        float d2 = di * di;
        if (tid < 16) {
            float4 a4 = ((const float4*)(agg + (size_t)node * 64))[tid];
            float4 x4 = ((const float4*)(x + (size_t)node * 64))[tid];
            a4.x = fmaf(x4.x, d2, a4.x);
            a4.y = fmaf(x4.y, d2, a4.y);
            a4.z = fmaf(x4.z, d2, a4.z);
            a4.w = fmaf(x4.w, d2, a4.w);
            ((float4*)sA)[tid] = a4;
        }
        __syncthreads();
        float accz = czj, acch = chj;
#pragma unroll
        for (int k4 = 0; k4 < 16; ++k4) {
            float4 a = ((const float4*)sA)[k4];   // ds_read_b128 broadcast
            accz = fmaf(a.x, mz[4 * k4 + 0], accz);
            acch = fmaf(a.x, mh[4 * k4 + 0], acch);
            accz = fmaf(a.y, mz[4 * k4 + 1], accz);
            acch = fmaf(a.y, mh[4 * k4 + 1], acch);
            accz = fmaf(a.z, mz[4 * k4 + 2], accz);
            acch = fmaf(a.z, mh[4 * k4 + 2], acch);
            accz = fmaf(a.w, mz[4 * k4 + 3], accz);
            acch = fmaf(a.w, mh[4 * k4 + 3], acch);
        }
        float z = 1.0f / (1.0f + __expf(-accz));
        float ht = tanhf(acch);
        float h = fmaxf((1.0f - z) * ht, 0.0f);
        float l0 = h * wo.x, l1 = h * wo.y, l2 = h * wo.z, l3 = h * wo.w;
#pragma unroll
        for (int off = 32; off > 0; off >>= 1) {
            l0 += __shfl_down(l0, off);
            l1 += __shfl_down(l1, off);
            l2 += __shfl_down(l2, off);
            l3 += __shfl_down(l3, off);
        }
        if ((tid & 63) == 0) {
            int w = tid >> 6;
            sRed[w * 4 + 0] = l0;
            sRed[w * 4 + 1] = l1;
            sRed[w * 4 + 2] = l2;
            sRed[w * 4 + 3] = l3;
        }
        __syncthreads();
        if (tid == 0) {
            float v0 = sRed[0] + sRed[4] + sRed[8] + sRed[12] + bo0;
            float v1 = sRed[1] + sRed[5] + sRed[9] + sRed[13] + bo1;
            float v2 = sRed[2] + sRed[6] + sRed[10] + sRed[14] + bo2;
            float v3 = sRed[3] + sRed[7] + sRed[11] + sRed[15] + bo3;
            float m = fmaxf(fmaxf(v0, v1), fmaxf(v2, v3));
            float e0 = __expf(v0 - m), e1 = __expf(v1 - m);
            float e2 = __expf(v2 - m), e3 = __expf(v3 - m);
            float inv = 1.0f / (e0 + e1 + e2 + e3);
            float4 o;
            o.x = e0 * inv; o.y = e1 * inv; o.z = e2 * inv; o.w = e3 * inv;
            ((float4*)out)[node] = o;
        }
        __syncthreads();
    }
}

extern "C" void kernel_launch(void* const* d_in, const int* in_sizes, int n_in,
                              void* d_out, int out_size, void* d_ws, size_t ws_size,
                              hipStream_t stream) {
    const float* x   = (const float*)d_in[0];
    const int*  eidx = (const int*)d_in[1];
    const float* Wz  = (const float*)d_in[2];
    const float* bz  = (const float*)d_in[3];
    // d_in[4]=Wr, d_in[5]=br : dead (H0 = 0)
    const float* Wh  = (const float*)d_in[6];
    const float* bh  = (const float*)d_in[7];
    const float* Lzw = (const float*)d_in[8];
    const float* Lzb = (const float*)d_in[9];
    // d_in[10]=Lrw, d_in[11]=Lrb : dead
    const float* Lhw = (const float*)d_in[12];
    const float* Lhb = (const float*)d_in[13];
    const float* Wo  = (const float*)d_in[14];
    const float* bo  = (const float*)d_in[15];
    float* out = (float*)d_out;

    int n = in_sizes[0] / 64;
    int E = in_sizes[1] / 2;
    const int* srcs = eidx;
    const int* dsts = eidx + E;

    size_t na = ((size_t)n + 3) & ~(size_t)3;
    float* ws   = (float*)d_ws;
    float* deg  = ws;
    float* dinv = deg + na;
    float* agg  = dinv + na;
    float* Mz   = agg + (size_t)n * 64;
    float* Mh   = Mz + 64 * 256;
    float* cz   = Mh + 64 * 256;
    float* ch   = cz + 256;

    hipMemsetAsync(deg, 0, (size_t)n * sizeof(float), stream);
    hipMemsetAsync(agg, 0, (size_t)n * 64 * sizeof(float), stream);

    deg_kernel<<<(E + 255) / 256, 256, 0, stream>>>(dsts, deg, E);
    dinv_kernel<<<(n + 255) / 256, 256, 0, stream>>>(deg, dinv, n);
    edge_agg_kernel<<<(int)(((size_t)E * 16 + 255) / 256), 256, 0, stream>>>(
        srcs, dsts, x, dinv, agg, E);
    build_m_kernel<<<dim3(65, 2), 256, 0, stream>>>(Wz, bz, Wh, bh, Lzw, Lzb, Lhw,
                                                    Lhb, Mz, cz, Mh, ch);
    node_kernel<<<2048, 256, 0, stream>>>(agg, x, dinv, Mz, cz, Mh, ch, Wo, bo,
                                          out, n);
}

// Round 2
// 942.428 us; speedup vs baseline: 3.4968x; 3.4968x over previous
//
#include <hip/hip_runtime.h>

// TGCN forward, algebraically reduced (H0 = 0 => R/Wr dead, Z*H = 0):
//   deg[d] = #in-edges of d ; dinv = rsqrt(deg+1)
//   agg[d] = dinv[d] * ( sum_{e: dst=d} x[src]*dinv[src] + x[d]*dinv[d] )
//   Mz = Wz @ Lzw[0:256], cz = bz @ Lzw[0:256] + Lzb   (same for h)
//   Z = sigmoid(agg@Mz + cz), Ht = tanh(agg@Mh + ch)
//   h = relu((1-Z)*Ht) ; out = softmax(h @ Wo + bo)
//
// R1 -> R2: edge scatter with 204.8M fp32 atomics (2700us, WRITE_SIZE 3.2GB,
// atomic-throughput bound) replaced by unordered-bucket CSR build (2x E int
// atomics) + deterministic per-node register gather.

__global__ __launch_bounds__(256) void deg_count_kernel(const int* __restrict__ dsts,
                                                        int* __restrict__ deg, int E) {
    int e = blockIdx.x * 256 + threadIdx.x;
    if (e < E) atomicAdd(&deg[dsts[e]], 1);
}

// bucket allocation: order across nodes is irrelevant, only contiguity matters
__global__ __launch_bounds__(256) void alloc_kernel(const int* __restrict__ deg,
                                                    int* __restrict__ start,
                                                    int* __restrict__ cursor,
                                                    float* __restrict__ dinv,
                                                    int* __restrict__ counter, int n) {
    int i = blockIdx.x * 256 + threadIdx.x;
    if (i < n) {
        int d = deg[i];
        int s = atomicAdd(counter, d);
        start[i] = s;
        cursor[i] = s;
        dinv[i] = rsqrtf((float)d + 1.0f);
    }
}

__global__ __launch_bounds__(256) void scatter_kernel(const int* __restrict__ srcs,
                                                      const int* __restrict__ dsts,
                                                      int* __restrict__ cursor,
                                                      int* __restrict__ csr, int E) {
    int e = blockIdx.x * 256 + threadIdx.x;
    if (e < E) {
        int pos = atomicAdd(&cursor[dsts[e]], 1);
        csr[pos] = srcs[e];
    }
}

// one wave per node (4 waves/block). Lane = (edge_group 0..3) x (chan_quad 0..15).
// Each iteration: 1 vmem instruction covers 4 edge rows (4 x 256B), fp32
// accumulate in registers, cross-edge-group reduce via shfl, single coalesced
// 256B agg write per node.
__global__ __launch_bounds__(256) void gather_kernel(const int* __restrict__ csr,
                                                     const int* __restrict__ start,
                                                     const int* __restrict__ deg,
                                                     const float* __restrict__ x,
                                                     const float* __restrict__ dinv,
                                                     float* __restrict__ agg, int n) {
    int wave = threadIdx.x >> 6;
    int lane = threadIdx.x & 63;
    int node = blockIdx.x * 4 + wave;
    if (node >= n) return;
    int eg = lane >> 4;      // edge group 0..3
    int c  = lane & 15;      // float4 channel quad
    int s0 = start[node];
    int d  = deg[node];
    const float4* x4 = (const float4*)x;
    float4 acc = make_float4(0.f, 0.f, 0.f, 0.f);
    for (int base = 0; base < d; base += 4) {
        int e = base + eg;
        if (e < d) {
            int s = csr[s0 + e];
            float ds = dinv[s];
            float4 v = x4[(size_t)s * 16 + c];
            acc.x = fmaf(v.x, ds, acc.x);
            acc.y = fmaf(v.y, ds, acc.y);
            acc.z = fmaf(v.z, ds, acc.z);
            acc.w = fmaf(v.w, ds, acc.w);
        }
    }
    // reduce the 4 edge groups down to lanes 0..15
    acc.x += __shfl_down(acc.x, 32); acc.y += __shfl_down(acc.y, 32);
    acc.z += __shfl_down(acc.z, 32); acc.w += __shfl_down(acc.w, 32);
    acc.x += __shfl_down(acc.x, 16); acc.y += __shfl_down(acc.y, 16);
    acc.z += __shfl_down(acc.z, 16); acc.w += __shfl_down(acc.w, 16);
    if (eg == 0) {
        float dn = dinv[node];
        float4 xv = x4[(size_t)node * 16 + c];
        float4 o;
        o.x = dn * fmaf(xv.x, dn, acc.x);
        o.y = dn * fmaf(xv.y, dn, acc.y);
        o.z = dn * fmaf(xv.z, dn, acc.z);
        o.w = dn * fmaf(xv.w, dn, acc.w);
        ((float4*)agg)[(size_t)node * 16 + c] = o;
    }
}

// Mz[k][j] = sum_t W[k][t] * L[t][j]   (k<64);  row k==64 computes the bias fold
__global__ __launch_bounds__(256) void build_m_kernel(
    const float* __restrict__ Wz, const float* __restrict__ bz,
    const float* __restrict__ Wh, const float* __restrict__ bh,
    const float* __restrict__ Lzw, const float* __restrict__ Lzb,
    const float* __restrict__ Lhw, const float* __restrict__ Lhb,
    float* __restrict__ Mz, float* __restrict__ cz,
    float* __restrict__ Mh, float* __restrict__ ch) {
    int j = threadIdx.x;
    int k = blockIdx.x;          // 0..64 (64 == bias row)
    int which = blockIdx.y;      // 0=z, 1=h
    const float* W  = which ? Wh  : Wz;
    const float* bv = which ? bh  : bz;
    const float* L  = which ? Lhw : Lzw;   // [512,256]; only rows 0..255 matter (H0=0)
    const float* Lb = which ? Lhb : Lzb;
    float* M  = which ? Mh : Mz;
    float* cv = which ? ch : cz;
    float acc = 0.f;
    if (k < 64) {
        for (int t = 0; t < 256; ++t) acc = fmaf(W[k * 256 + t], L[t * 256 + j], acc);
        M[k * 256 + j] = acc;
    } else {
        for (int t = 0; t < 256; ++t) acc = fmaf(bv[t], L[t * 256 + j], acc);
        cv[j] = acc + Lb[j];
    }
}

// one block per node-slice; thread j owns output channel j; M columns live in
// 128 VGPRs, agg row broadcast from LDS via float4 reads
__global__ __launch_bounds__(256) void node_kernel(
    const float* __restrict__ agg,
    const float* __restrict__ Mz, const float* __restrict__ cz,
    const float* __restrict__ Mh, const float* __restrict__ ch,
    const float* __restrict__ Wo, const float* __restrict__ bo,
    float* __restrict__ out, int n) {
    int tid = threadIdx.x;
    float mz[64], mh[64];
#pragma unroll
    for (int k = 0; k < 64; ++k) {
        mz[k] = Mz[k * 256 + tid];
        mh[k] = Mh[k * 256 + tid];
    }
    float czj = cz[tid], chj = ch[tid];
    float4 wo = ((const float4*)Wo)[tid];   // Wo row tid: [256,4] row-major
    float bo0 = bo[0], bo1 = bo[1], bo2 = bo[2], bo3 = bo[3];
    __shared__ __align__(16) float sA[64];
    __shared__ float sRed[16];
    for (int node = blockIdx.x; node < n; node += gridDim.x) {
        if (tid < 16) {
            ((float4*)sA)[tid] = ((const float4*)(agg + (size_t)node * 64))[tid];
        }
        __syncthreads();
        float accz = czj, acch = chj;
#pragma unroll
        for (int k4 = 0; k4 < 16; ++k4) {
            float4 a = ((const float4*)sA)[k4];   // ds_read_b128 broadcast
            accz = fmaf(a.x, mz[4 * k4 + 0], accz);
            acch = fmaf(a.x, mh[4 * k4 + 0], acch);
            accz = fmaf(a.y, mz[4 * k4 + 1], accz);
            acch = fmaf(a.y, mh[4 * k4 + 1], acch);
            accz = fmaf(a.z, mz[4 * k4 + 2], accz);
            acch = fmaf(a.z, mh[4 * k4 + 2], acch);
            accz = fmaf(a.w, mz[4 * k4 + 3], accz);
            acch = fmaf(a.w, mh[4 * k4 + 3], acch);
        }
        float z = 1.0f / (1.0f + __expf(-accz));
        float ht = tanhf(acch);
        float h = fmaxf((1.0f - z) * ht, 0.0f);
        float l0 = h * wo.x, l1 = h * wo.y, l2 = h * wo.z, l3 = h * wo.w;
#pragma unroll
        for (int off = 32; off > 0; off >>= 1) {
            l0 += __shfl_down(l0, off);
            l1 += __shfl_down(l1, off);
            l2 += __shfl_down(l2, off);
            l3 += __shfl_down(l3, off);
        }
        if ((tid & 63) == 0) {
            int w = tid >> 6;
            sRed[w * 4 + 0] = l0;
            sRed[w * 4 + 1] = l1;
            sRed[w * 4 + 2] = l2;
            sRed[w * 4 + 3] = l3;
        }
        __syncthreads();
        if (tid == 0) {
            float v0 = sRed[0] + sRed[4] + sRed[8] + sRed[12] + bo0;
            float v1 = sRed[1] + sRed[5] + sRed[9] + sRed[13] + bo1;
            float v2 = sRed[2] + sRed[6] + sRed[10] + sRed[14] + bo2;
            float v3 = sRed[3] + sRed[7] + sRed[11] + sRed[15] + bo3;
            float m = fmaxf(fmaxf(v0, v1), fmaxf(v2, v3));
            float e0 = __expf(v0 - m), e1 = __expf(v1 - m);
            float e2 = __expf(v2 - m), e3 = __expf(v3 - m);
            float inv = 1.0f / (e0 + e1 + e2 + e3);
            float4 o;
            o.x = e0 * inv; o.y = e1 * inv; o.z = e2 * inv; o.w = e3 * inv;
            ((float4*)out)[node] = o;
        }
        __syncthreads();
    }
}

extern "C" void kernel_launch(void* const* d_in, const int* in_sizes, int n_in,
                              void* d_out, int out_size, void* d_ws, size_t ws_size,
                              hipStream_t stream) {
    const float* x   = (const float*)d_in[0];
    const int*  eidx = (const int*)d_in[1];
    const float* Wz  = (const float*)d_in[2];
    const float* bz  = (const float*)d_in[3];
    // d_in[4]=Wr, d_in[5]=br : dead (H0 = 0)
    const float* Wh  = (const float*)d_in[6];
    const float* bh  = (const float*)d_in[7];
    const float* Lzw = (const float*)d_in[8];
    const float* Lzb = (const float*)d_in[9];
    // d_in[10]=Lrw, d_in[11]=Lrb : dead
    const float* Lhw = (const float*)d_in[12];
    const float* Lhb = (const float*)d_in[13];
    const float* Wo  = (const float*)d_in[14];
    const float* bo  = (const float*)d_in[15];
    float* out = (float*)d_out;

    int n = in_sizes[0] / 64;
    int E = in_sizes[1] / 2;
    const int* srcs = eidx;
    const int* dsts = eidx + E;

    size_t na = ((size_t)n + 3) & ~(size_t)3;
    char* ws = (char*)d_ws;
    int*   deg     = (int*)ws;                  ws += na * 4;
    int*   start   = (int*)ws;                  ws += na * 4;
    int*   cursor  = (int*)ws;                  ws += na * 4;
    int*   counter = (int*)ws;                  ws += 16;
    float* dinv    = (float*)ws;                ws += na * 4;
    int*   csr     = (int*)ws;                  ws += (size_t)E * 4;
    float* agg     = (float*)ws;                ws += (size_t)n * 64 * 4;
    float* Mz      = (float*)ws;                ws += 64 * 256 * 4;
    float* Mh      = (float*)ws;                ws += 64 * 256 * 4;
    float* cz      = (float*)ws;                ws += 256 * 4;
    float* ch      = (float*)ws;                ws += 256 * 4;

    hipMemsetAsync(deg, 0, (size_t)n * sizeof(int), stream);
    hipMemsetAsync(counter, 0, sizeof(int), stream);

    deg_count_kernel<<<(E + 255) / 256, 256, 0, stream>>>(dsts, deg, E);
    alloc_kernel<<<(n + 255) / 256, 256, 0, stream>>>(deg, start, cursor, dinv,
                                                      counter, n);
    scatter_kernel<<<(E + 255) / 256, 256, 0, stream>>>(srcs, dsts, cursor, csr, E);
    build_m_kernel<<<dim3(65, 2), 256, 0, stream>>>(Wz, bz, Wh, bh, Lzw, Lzb, Lhw,
                                                    Lhb, Mz, cz, Mh, ch);
    gather_kernel<<<(n + 3) / 4, 256, 0, stream>>>(csr, start, deg, x, dinv, agg, n);
    node_kernel<<<2048, 256, 0, stream>>>(agg, Mz, cz, Mh, ch, Wo, bo, out, n);
}

// Round 3
// 793.181 us; speedup vs baseline: 4.1547x; 1.1882x over previous
//
#include <hip/hip_runtime.h>

// TGCN forward, algebraically reduced (H0 = 0 => R/Wr dead, Z*H = 0):
//   deg[d] = #in-edges of d ; dinv = rsqrt(deg+1)
//   agg[d] = dinv[d] * ( sum_{e: dst=d} x[src]*dinv[src] + x[d]*dinv[d] )
//   Mz = Wz @ Lzw[0:256], cz = bz @ Lzw[0:256] + Lzb   (same for h)
//   Z = sigmoid(agg@Mz + cz), Ht = tanh(agg@Mh + ch)
//   h = relu((1-Z)*Ht) ; out = softmax(h @ Wo + bo)
//
// R1 -> R2: atomic scatter (2700us) -> CSR build + register gather.
// R2 -> R3: node_kernel was overhead-bound (VALUBusy 40%, 2 barriers + 24-lane
// shuffle tree PER NODE). Now 8 nodes/tile: 1024 FMAs per barrier pair, head
// reduction via LDS transpose + width-32 shuffle (amortized ~8%), agg memset
// dropped (gather overwrites).

__global__ __launch_bounds__(256) void deg_count_kernel(const int* __restrict__ dsts,
                                                        int* __restrict__ deg, int E) {
    int e = blockIdx.x * 256 + threadIdx.x;
    if (e < E) atomicAdd(&deg[dsts[e]], 1);
}

// bucket allocation: order across nodes is irrelevant, only contiguity matters
__global__ __launch_bounds__(256) void alloc_kernel(const int* __restrict__ deg,
                                                    int* __restrict__ start,
                                                    int* __restrict__ cursor,
                                                    float* __restrict__ dinv,
                                                    int* __restrict__ counter, int n) {
    int i = blockIdx.x * 256 + threadIdx.x;
    if (i < n) {
        int d = deg[i];
        int s = atomicAdd(counter, d);
        start[i] = s;
        cursor[i] = s;
        dinv[i] = rsqrtf((float)d + 1.0f);
    }
}

__global__ __launch_bounds__(256) void scatter_kernel(const int* __restrict__ srcs,
                                                      const int* __restrict__ dsts,
                                                      int* __restrict__ cursor,
                                                      int* __restrict__ csr, int E) {
    int e = blockIdx.x * 256 + threadIdx.x;
    if (e < E) {
        int pos = atomicAdd(&cursor[dsts[e]], 1);
        csr[pos] = srcs[e];
    }
}

// one wave per node (4 waves/block). Lane = (edge_group 0..3) x (chan_quad 0..15).
__global__ __launch_bounds__(256) void gather_kernel(const int* __restrict__ csr,
                                                     const int* __restrict__ start,
                                                     const int* __restrict__ deg,
                                                     const float* __restrict__ x,
                                                     const float* __restrict__ dinv,
                                                     float* __restrict__ agg, int n) {
    int wave = threadIdx.x >> 6;
    int lane = threadIdx.x & 63;
    int node = blockIdx.x * 4 + wave;
    if (node >= n) return;
    int eg = lane >> 4;      // edge group 0..3
    int c  = lane & 15;      // float4 channel quad
    int s0 = start[node];
    int d  = deg[node];
    const float4* x4 = (const float4*)x;
    float4 acc = make_float4(0.f, 0.f, 0.f, 0.f);
    for (int base = 0; base < d; base += 4) {
        int e = base + eg;
        if (e < d) {
            int s = csr[s0 + e];
            float ds = dinv[s];
            float4 v = x4[(size_t)s * 16 + c];
            acc.x = fmaf(v.x, ds, acc.x);
            acc.y = fmaf(v.y, ds, acc.y);
            acc.z = fmaf(v.z, ds, acc.z);
            acc.w = fmaf(v.w, ds, acc.w);
        }
    }
    // reduce the 4 edge groups down to lanes 0..15
    acc.x += __shfl_down(acc.x, 32); acc.y += __shfl_down(acc.y, 32);
    acc.z += __shfl_down(acc.z, 32); acc.w += __shfl_down(acc.w, 32);
    acc.x += __shfl_down(acc.x, 16); acc.y += __shfl_down(acc.y, 16);
    acc.z += __shfl_down(acc.z, 16); acc.w += __shfl_down(acc.w, 16);
    if (eg == 0) {
        float dn = dinv[node];
        float4 xv = x4[(size_t)node * 16 + c];
        float4 o;
        o.x = dn * fmaf(xv.x, dn, acc.x);
        o.y = dn * fmaf(xv.y, dn, acc.y);
        o.z = dn * fmaf(xv.z, dn, acc.z);
        o.w = dn * fmaf(xv.w, dn, acc.w);
        ((float4*)agg)[(size_t)node * 16 + c] = o;
    }
}

// Mz[k][j] = sum_t W[k][t] * L[t][j]   (k<64);  row k==64 computes the bias fold
__global__ __launch_bounds__(256) void build_m_kernel(
    const float* __restrict__ Wz, const float* __restrict__ bz,
    const float* __restrict__ Wh, const float* __restrict__ bh,
    const float* __restrict__ Lzw, const float* __restrict__ Lzb,
    const float* __restrict__ Lhw, const float* __restrict__ Lhb,
    float* __restrict__ Mz, float* __restrict__ cz,
    float* __restrict__ Mh, float* __restrict__ ch) {
    int j = threadIdx.x;
    int k = blockIdx.x;          // 0..64 (64 == bias row)
    int which = blockIdx.y;      // 0=z, 1=h
    const float* W  = which ? Wh  : Wz;
    const float* bv = which ? bh  : bz;
    const float* L  = which ? Lhw : Lzw;   // [512,256]; only rows 0..255 matter (H0=0)
    const float* Lb = which ? Lhb : Lzb;
    float* M  = which ? Mh : Mz;
    float* cv = which ? ch : cz;
    float acc = 0.f;
    if (k < 64) {
        for (int t = 0; t < 256; ++t) acc = fmaf(W[k * 256 + t], L[t * 256 + j], acc);
        M[k * 256 + j] = acc;
    } else {
        for (int t = 0; t < 256; ++t) acc = fmaf(bv[t], L[t * 256 + j], acc);
        cv[j] = acc + Lb[j];
    }
}

#define NB 8   // nodes per block-iteration

// thread j owns output channel j; M columns in 128 VGPRs; 8-node tile:
// load agg tile -> barrier -> 1024 FMAs/thread -> LDS transpose of h ->
// barrier -> 32 threads/node head reduce (width-32 shuffle) -> softmax write.
__global__ __launch_bounds__(256) void node_kernel(
    const float* __restrict__ agg,
    const float* __restrict__ Mz, const float* __restrict__ cz,
    const float* __restrict__ Mh, const float* __restrict__ ch,
    const float* __restrict__ Wo, const float* __restrict__ bo,
    float* __restrict__ out, int n) {
    int tid = threadIdx.x;
    float mz[64], mh[64];
#pragma unroll
    for (int k = 0; k < 64; ++k) {
        mz[k] = Mz[k * 256 + tid];
        mh[k] = Mh[k * 256 + tid];
    }
    float czj = cz[tid], chj = ch[tid];
    __shared__ __align__(16) float sA[NB * 64];   // 2 KB agg tile
    __shared__ float sH[NB * 256];                // 8 KB h transpose
    __shared__ float sWo[4][256];                 // 4 KB Wo planar (2-way max alias)
#pragma unroll
    for (int o = 0; o < 4; ++o) sWo[o][tid] = Wo[tid * 4 + o];
    float bo0 = bo[0], bo1 = bo[1], bo2 = bo[2], bo3 = bo[3];
    int ntiles = (n + NB - 1) / NB;
    for (int tile = blockIdx.x; tile < ntiles; tile += gridDim.x) {
        int node0 = tile * NB;
        if (tid < NB * 16) {   // coalesced tile load: 128 float4
            int nb = tid >> 4, q = tid & 15;
            int node = node0 + nb;
            ((float4*)sA)[tid] = (node < n)
                ? ((const float4*)agg)[(size_t)node * 16 + q]
                : make_float4(0.f, 0.f, 0.f, 0.f);
        }
        __syncthreads();
#pragma unroll
        for (int nb = 0; nb < NB; ++nb) {
            float az = czj, ah = chj;
#pragma unroll
            for (int k4 = 0; k4 < 16; ++k4) {
                float4 a = ((float4*)sA)[nb * 16 + k4];  // uniform addr: broadcast
                az = fmaf(a.x, mz[4 * k4 + 0], az);
                ah = fmaf(a.x, mh[4 * k4 + 0], ah);
                az = fmaf(a.y, mz[4 * k4 + 1], az);
                ah = fmaf(a.y, mh[4 * k4 + 1], ah);
                az = fmaf(a.z, mz[4 * k4 + 2], az);
                ah = fmaf(a.z, mh[4 * k4 + 2], ah);
                az = fmaf(a.w, mz[4 * k4 + 3], az);
                ah = fmaf(a.w, mh[4 * k4 + 3], ah);
            }
            float z = 1.0f / (1.0f + __expf(-az));
            float t = 1.0f - 2.0f / (1.0f + __expf(2.0f * ah));  // tanh
            sH[nb * 256 + tid] = fmaxf((1.0f - z) * t, 0.0f);
        }
        __syncthreads();
        {   // head: 32 threads per node
            int nb = tid >> 5, g = tid & 31;
            float l0 = 0.f, l1 = 0.f, l2 = 0.f, l3 = 0.f;
#pragma unroll
            for (int i = 0; i < 8; ++i) {
                int c = g + 32 * i;
                float hv = sH[nb * 256 + c];
                l0 = fmaf(hv, sWo[0][c], l0);
                l1 = fmaf(hv, sWo[1][c], l1);
                l2 = fmaf(hv, sWo[2][c], l2);
                l3 = fmaf(hv, sWo[3][c], l3);
            }
#pragma unroll
            for (int off = 16; off > 0; off >>= 1) {
                l0 += __shfl_down(l0, off, 32);
                l1 += __shfl_down(l1, off, 32);
                l2 += __shfl_down(l2, off, 32);
                l3 += __shfl_down(l3, off, 32);
            }
            int node = node0 + nb;
            if (g == 0 && node < n) {
                float v0 = l0 + bo0, v1 = l1 + bo1, v2 = l2 + bo2, v3 = l3 + bo3;
                float m = fmaxf(fmaxf(v0, v1), fmaxf(v2, v3));
                float e0 = __expf(v0 - m), e1 = __expf(v1 - m);
                float e2 = __expf(v2 - m), e3 = __expf(v3 - m);
                float inv = 1.0f / (e0 + e1 + e2 + e3);
                float4 o;
                o.x = e0 * inv; o.y = e1 * inv; o.z = e2 * inv; o.w = e3 * inv;
                ((float4*)out)[node] = o;
            }
        }
        __syncthreads();
    }
}

extern "C" void kernel_launch(void* const* d_in, const int* in_sizes, int n_in,
                              void* d_out, int out_size, void* d_ws, size_t ws_size,
                              hipStream_t stream) {
    const float* x   = (const float*)d_in[0];
    const int*  eidx = (const int*)d_in[1];
    const float* Wz  = (const float*)d_in[2];
    const float* bz  = (const float*)d_in[3];
    // d_in[4]=Wr, d_in[5]=br : dead (H0 = 0)
    const float* Wh  = (const float*)d_in[6];
    const float* bh  = (const float*)d_in[7];
    const float* Lzw = (const float*)d_in[8];
    const float* Lzb = (const float*)d_in[9];
    // d_in[10]=Lrw, d_in[11]=Lrb : dead
    const float* Lhw = (const float*)d_in[12];
    const float* Lhb = (const float*)d_in[13];
    const float* Wo  = (const float*)d_in[14];
    const float* bo  = (const float*)d_in[15];
    float* out = (float*)d_out;

    int n = in_sizes[0] / 64;
    int E = in_sizes[1] / 2;
    const int* srcs = eidx;
    const int* dsts = eidx + E;

    size_t na = ((size_t)n + 3) & ~(size_t)3;
    char* ws = (char*)d_ws;
    int*   deg     = (int*)ws;                  ws += na * 4;
    int*   start   = (int*)ws;                  ws += na * 4;
    int*   cursor  = (int*)ws;                  ws += na * 4;
    int*   counter = (int*)ws;                  ws += 16;
    float* dinv    = (float*)ws;                ws += na * 4;
    int*   csr     = (int*)ws;                  ws += (size_t)E * 4;
    float* agg     = (float*)ws;                ws += (size_t)n * 64 * 4;
    float* Mz      = (float*)ws;                ws += 64 * 256 * 4;
    float* Mh      = (float*)ws;                ws += 64 * 256 * 4;
    float* cz      = (float*)ws;                ws += 256 * 4;
    float* ch      = (float*)ws;                ws += 256 * 4;

    hipMemsetAsync(deg, 0, (size_t)n * sizeof(int), stream);
    hipMemsetAsync(counter, 0, sizeof(int), stream);

    deg_count_kernel<<<(E + 255) / 256, 256, 0, stream>>>(dsts, deg, E);
    alloc_kernel<<<(n + 255) / 256, 256, 0, stream>>>(deg, start, cursor, dinv,
                                                      counter, n);
    scatter_kernel<<<(E + 255) / 256, 256, 0, stream>>>(srcs, dsts, cursor, csr, E);
    build_m_kernel<<<dim3(65, 2), 256, 0, stream>>>(Wz, bz, Wh, bh, Lzw, Lzb, Lhw,
                                                    Lhb, Mz, cz, Mh, ch);
    gather_kernel<<<(n + 3) / 4, 256, 0, stream>>>(csr, start, deg, x, dinv, agg, n);
    node_kernel<<<2048, 256, 0, stream>>>(agg, Mz, cz, Mh, ch, Wo, bo, out, n);
}

// Round 4
// 455.188 us; speedup vs baseline: 7.2398x; 1.7425x over previous
//
#include <hip/hip_runtime.h>

// TGCN forward, algebraically reduced (H0 = 0 => R/Wr dead, Z*H = 0):
//   deg[d] = #in-edges of d ; dinv = rsqrt(deg+1)
//   agg[d] = dinv[d] * ( sum_{e: dst=d} x[src]*dinv[src] + x[d]*dinv[d] )
//   Mz = Wz @ Lzw[0:256], cz = bz @ Lzw[0:256] + Lzb   (same for h)
//   Z = sigmoid(agg@Mz + cz), Ht = tanh(agg@Mh + ch)
//   h = relu((1-Z)*Ht) ; out = softmax(h @ Wo + bo)
//
// R1 -> R2: atomic scatter (2700us) -> CSR build + register gather.
// R2 -> R3: node_kernel 8-node tiling (313us -> off the top-5).
// R3 -> R4: scatter_kernel wrote 194MB HBM for a 12.8MB csr (16x write amp:
// random 4B stores, lines shared across XCDs). Replaced by 2-level bucket
// sort: bucket hist + prefix, LDS-staged binning into per-bucket regions
// (contiguous ~21-entry runs), then per-bucket finalize scattering inside a
// block-PRIVATE 32KB window (lines stay in one XCD's L2, ~1x write amp).

#define SHIFT 8
#define NPB   256          // nodes per bucket (=1<<SHIFT)
#define BMAX  512          // max buckets (n <= 131072 for 17-bit src packing)
#define TILE  8192         // edges per binning block
#define EPT   32           // edges per thread in binning

__global__ __launch_bounds__(256) void bucket_hist_kernel(const int* __restrict__ dsts,
                                                          int* __restrict__ bdeg,
                                                          int E, int B) {
    __shared__ int h[BMAX];
    for (int i = threadIdx.x; i < B; i += 256) h[i] = 0;
    __syncthreads();
    for (int e = blockIdx.x * 256 + threadIdx.x; e < E; e += gridDim.x * 256)
        atomicAdd(&h[((unsigned)dsts[e]) >> SHIFT], 1);
    __syncthreads();
    for (int i = threadIdx.x; i < B; i += 256)
        if (h[i]) atomicAdd(&bdeg[i], h[i]);
}

__global__ __launch_bounds__(512) void bucket_prefix_kernel(const int* __restrict__ bdeg,
                                                            int* __restrict__ bbase,
                                                            int* __restrict__ bcur, int B) {
    __shared__ int sv[BMAX];
    int tid = threadIdx.x;
    int v = (tid < B) ? bdeg[tid] : 0;
    sv[tid] = v;
    __syncthreads();
    for (int off = 1; off < BMAX; off <<= 1) {
        int t = (tid >= off) ? sv[tid - off] : 0;
        __syncthreads();
        sv[tid] += t;
        __syncthreads();
    }
    int excl = sv[tid] - v;
    if (tid < B) { bbase[tid] = excl; bcur[tid] = excl; }
}

// tile of 8192 edges: LDS histogram -> one global cursor atomic per
// (block,bucket) -> packed (dstLocal<<17 | src) written in contiguous runs
__global__ __launch_bounds__(256) void binning_kernel(const int* __restrict__ srcs,
                                                      const int* __restrict__ dsts,
                                                      int* __restrict__ bcur,
                                                      int* __restrict__ staging,
                                                      int E, int B) {
    __shared__ int h[BMAX];
    __shared__ int cur[BMAX];
    int tile0 = blockIdx.x * TILE;
    for (int i = threadIdx.x; i < B; i += 256) h[i] = 0;
    __syncthreads();
#pragma unroll 4
    for (int j = 0; j < EPT; ++j) {
        int e = tile0 + j * 256 + threadIdx.x;
        if (e < E) atomicAdd(&h[((unsigned)dsts[e]) >> SHIFT], 1);
    }
    __syncthreads();
    for (int i = threadIdx.x; i < B; i += 256)
        cur[i] = h[i] ? atomicAdd(&bcur[i], h[i]) : 0;
    __syncthreads();
#pragma unroll 4
    for (int j = 0; j < EPT; ++j) {
        int e = tile0 + j * 256 + threadIdx.x;
        if (e < E) {
            int d = dsts[e], s = srcs[e];
            int b = ((unsigned)d) >> SHIFT;
            int pos = atomicAdd(&cur[b], 1);
            staging[pos] = ((d & (NPB - 1)) << 17) | s;
        }
    }
}

// one block per bucket: per-node LDS histogram + scan -> start/deg/dinv,
// then scatter srcs inside the bucket's private csr window
__global__ __launch_bounds__(256) void finalize_kernel(const int* __restrict__ staging,
                                                       const int* __restrict__ bdeg,
                                                       const int* __restrict__ bbase,
                                                       int* __restrict__ csr,
                                                       int* __restrict__ deg,
                                                       int* __restrict__ start,
                                                       float* __restrict__ dinv, int n) {
    int b = blockIdx.x;
    int base = bbase[b], count = bdeg[b];
    __shared__ int nd[NPB];
    __shared__ int sv[NPB];
    __shared__ int ncur[NPB];
    int tid = threadIdx.x;
    nd[tid] = 0;
    __syncthreads();
    for (int i = tid; i < count; i += 256)
        atomicAdd(&nd[staging[base + i] >> 17], 1);
    __syncthreads();
    int d0 = nd[tid];
    sv[tid] = d0;
    __syncthreads();
    for (int off = 1; off < NPB; off <<= 1) {
        int t = (tid >= off) ? sv[tid - off] : 0;
        __syncthreads();
        sv[tid] += t;
        __syncthreads();
    }
    int excl = sv[tid] - d0;
    ncur[tid] = excl;
    int node = (b << SHIFT) + tid;
    if (node < n) {
        start[node] = base + excl;
        deg[node] = d0;
        dinv[node] = rsqrtf((float)d0 + 1.0f);
    }
    __syncthreads();
    for (int i = tid; i < count; i += 256) {
        int p = staging[base + i];
        int pos = atomicAdd(&ncur[p >> 17], 1);
        csr[base + pos] = p & 0x1FFFF;
    }
}

// one wave per node (4 waves/block). Lane = (edge_group 0..3) x (chan_quad 0..15).
__global__ __launch_bounds__(256) void gather_kernel(const int* __restrict__ csr,
                                                     const int* __restrict__ start,
                                                     const int* __restrict__ deg,
                                                     const float* __restrict__ x,
                                                     const float* __restrict__ dinv,
                                                     float* __restrict__ agg, int n) {
    int wave = threadIdx.x >> 6;
    int lane = threadIdx.x & 63;
    int node = blockIdx.x * 4 + wave;
    if (node >= n) return;
    int eg = lane >> 4;      // edge group 0..3
    int c  = lane & 15;      // float4 channel quad
    int s0 = start[node];
    int d  = deg[node];
    const float4* x4 = (const float4*)x;
    float4 acc = make_float4(0.f, 0.f, 0.f, 0.f);
    for (int base = 0; base < d; base += 4) {
        int e = base + eg;
        if (e < d) {
            int s = csr[s0 + e];
            float ds = dinv[s];
            float4 v = x4[(size_t)s * 16 + c];
            acc.x = fmaf(v.x, ds, acc.x);
            acc.y = fmaf(v.y, ds, acc.y);
            acc.z = fmaf(v.z, ds, acc.z);
            acc.w = fmaf(v.w, ds, acc.w);
        }
    }
    acc.x += __shfl_down(acc.x, 32); acc.y += __shfl_down(acc.y, 32);
    acc.z += __shfl_down(acc.z, 32); acc.w += __shfl_down(acc.w, 32);
    acc.x += __shfl_down(acc.x, 16); acc.y += __shfl_down(acc.y, 16);
    acc.z += __shfl_down(acc.z, 16); acc.w += __shfl_down(acc.w, 16);
    if (eg == 0) {
        float dn = dinv[node];
        float4 xv = x4[(size_t)node * 16 + c];
        float4 o;
        o.x = dn * fmaf(xv.x, dn, acc.x);
        o.y = dn * fmaf(xv.y, dn, acc.y);
        o.z = dn * fmaf(xv.z, dn, acc.z);
        o.w = dn * fmaf(xv.w, dn, acc.w);
        ((float4*)agg)[(size_t)node * 16 + c] = o;
    }
}

// Mz[k][j] = sum_t W[k][t] * L[t][j]   (k<64);  row k==64 computes the bias fold
__global__ __launch_bounds__(256) void build_m_kernel(
    const float* __restrict__ Wz, const float* __restrict__ bz,
    const float* __restrict__ Wh, const float* __restrict__ bh,
    const float* __restrict__ Lzw, const float* __restrict__ Lzb,
    const float* __restrict__ Lhw, const float* __restrict__ Lhb,
    float* __restrict__ Mz, float* __restrict__ cz,
    float* __restrict__ Mh, float* __restrict__ ch) {
    int j = threadIdx.x;
    int k = blockIdx.x;          // 0..64 (64 == bias row)
    int which = blockIdx.y;      // 0=z, 1=h
    const float* W  = which ? Wh  : Wz;
    const float* bv = which ? bh  : bz;
    const float* L  = which ? Lhw : Lzw;   // [512,256]; only rows 0..255 matter (H0=0)
    const float* Lb = which ? Lhb : Lzb;
    float* M  = which ? Mh : Mz;
    float* cv = which ? ch : cz;
    float acc = 0.f;
    if (k < 64) {
        for (int t = 0; t < 256; ++t) acc = fmaf(W[k * 256 + t], L[t * 256 + j], acc);
        M[k * 256 + j] = acc;
    } else {
        for (int t = 0; t < 256; ++t) acc = fmaf(bv[t], L[t * 256 + j], acc);
        cv[j] = acc + Lb[j];
    }
}

#define NB 8   // nodes per block-iteration

__global__ __launch_bounds__(256) void node_kernel(
    const float* __restrict__ agg,
    const float* __restrict__ Mz, const float* __restrict__ cz,
    const float* __restrict__ Mh, const float* __restrict__ ch,
    const float* __restrict__ Wo, const float* __restrict__ bo,
    float* __restrict__ out, int n) {
    int tid = threadIdx.x;
    float mz[64], mh[64];
#pragma unroll
    for (int k = 0; k < 64; ++k) {
        mz[k] = Mz[k * 256 + tid];
        mh[k] = Mh[k * 256 + tid];
    }
    float czj = cz[tid], chj = ch[tid];
    __shared__ __align__(16) float sA[NB * 64];
    __shared__ float sH[NB * 256];
    __shared__ float sWo[4][256];
#pragma unroll
    for (int o = 0; o < 4; ++o) sWo[o][tid] = Wo[tid * 4 + o];
    float bo0 = bo[0], bo1 = bo[1], bo2 = bo[2], bo3 = bo[3];
    int ntiles = (n + NB - 1) / NB;
    for (int tile = blockIdx.x; tile < ntiles; tile += gridDim.x) {
        int node0 = tile * NB;
        if (tid < NB * 16) {
            int nb = tid >> 4, q = tid & 15;
            int node = node0 + nb;
            ((float4*)sA)[tid] = (node < n)
                ? ((const float4*)agg)[(size_t)node * 16 + q]
                : make_float4(0.f, 0.f, 0.f, 0.f);
        }
        __syncthreads();
#pragma unroll
        for (int nb = 0; nb < NB; ++nb) {
            float az = czj, ah = chj;
#pragma unroll
            for (int k4 = 0; k4 < 16; ++k4) {
                float4 a = ((float4*)sA)[nb * 16 + k4];
                az = fmaf(a.x, mz[4 * k4 + 0], az);
                ah = fmaf(a.x, mh[4 * k4 + 0], ah);
                az = fmaf(a.y, mz[4 * k4 + 1], az);
                ah = fmaf(a.y, mh[4 * k4 + 1], ah);
                az = fmaf(a.z, mz[4 * k4 + 2], az);
                ah = fmaf(a.z, mh[4 * k4 + 2], ah);
                az = fmaf(a.w, mz[4 * k4 + 3], az);
                ah = fmaf(a.w, mh[4 * k4 + 3], ah);
            }
            float z = 1.0f / (1.0f + __expf(-az));
            float t = 1.0f - 2.0f / (1.0f + __expf(2.0f * ah));  // tanh
            sH[nb * 256 + tid] = fmaxf((1.0f - z) * t, 0.0f);
        }
        __syncthreads();
        {
            int nb = tid >> 5, g = tid & 31;
            float l0 = 0.f, l1 = 0.f, l2 = 0.f, l3 = 0.f;
#pragma unroll
            for (int i = 0; i < 8; ++i) {
                int c = g + 32 * i;
                float hv = sH[nb * 256 + c];
                l0 = fmaf(hv, sWo[0][c], l0);
                l1 = fmaf(hv, sWo[1][c], l1);
                l2 = fmaf(hv, sWo[2][c], l2);
                l3 = fmaf(hv, sWo[3][c], l3);
            }
#pragma unroll
            for (int off = 16; off > 0; off >>= 1) {
                l0 += __shfl_down(l0, off, 32);
                l1 += __shfl_down(l1, off, 32);
                l2 += __shfl_down(l2, off, 32);
                l3 += __shfl_down(l3, off, 32);
            }
            int node = node0 + nb;
            if (g == 0 && node < n) {
                float v0 = l0 + bo0, v1 = l1 + bo1, v2 = l2 + bo2, v3 = l3 + bo3;
                float m = fmaxf(fmaxf(v0, v1), fmaxf(v2, v3));
                float e0 = __expf(v0 - m), e1 = __expf(v1 - m);
                float e2 = __expf(v2 - m), e3 = __expf(v3 - m);
                float inv = 1.0f / (e0 + e1 + e2 + e3);
                float4 o;
                o.x = e0 * inv; o.y = e1 * inv; o.z = e2 * inv; o.w = e3 * inv;
                ((float4*)out)[node] = o;
            }
        }
        __syncthreads();
    }
}

extern "C" void kernel_launch(void* const* d_in, const int* in_sizes, int n_in,
                              void* d_out, int out_size, void* d_ws, size_t ws_size,
                              hipStream_t stream) {
    const float* x   = (const float*)d_in[0];
    const int*  eidx = (const int*)d_in[1];
    const float* Wz  = (const float*)d_in[2];
    const float* bz  = (const float*)d_in[3];
    // d_in[4]=Wr, d_in[5]=br : dead (H0 = 0)
    const float* Wh  = (const float*)d_in[6];
    const float* bh  = (const float*)d_in[7];
    const float* Lzw = (const float*)d_in[8];
    const float* Lzb = (const float*)d_in[9];
    // d_in[10]=Lrw, d_in[11]=Lrb : dead
    const float* Lhw = (const float*)d_in[12];
    const float* Lhb = (const float*)d_in[13];
    const float* Wo  = (const float*)d_in[14];
    const float* bo  = (const float*)d_in[15];
    float* out = (float*)d_out;

    int n = in_sizes[0] / 64;
    int E = in_sizes[1] / 2;
    const int* srcs = eidx;
    const int* dsts = eidx + E;
    int B = (n + NPB - 1) >> SHIFT;

    size_t na = ((size_t)n + 3) & ~(size_t)3;
    char* ws = (char*)d_ws;
    int*   deg   = (int*)ws;    ws += na * 4;
    int*   start = (int*)ws;    ws += na * 4;
    float* dinv  = (float*)ws;  ws += na * 4;
    int*   bdeg  = (int*)ws;    ws += BMAX * 4;
    int*   bbase = (int*)ws;    ws += BMAX * 4;
    int*   bcur  = (int*)ws;    ws += BMAX * 4;
    int*   csr   = (int*)ws;    ws += (size_t)E * 4;
    float* agg   = (float*)ws;  ws += (size_t)n * 64 * 4;
    int*   staging = (int*)agg;   // aliases agg: staging dead before gather writes
    float* Mz    = (float*)ws;  ws += 64 * 256 * 4;
    float* Mh    = (float*)ws;  ws += 64 * 256 * 4;
    float* cz    = (float*)ws;  ws += 256 * 4;
    float* ch    = (float*)ws;  ws += 256 * 4;

    hipMemsetAsync(bdeg, 0, BMAX * sizeof(int), stream);

    bucket_hist_kernel<<<1024, 256, 0, stream>>>(dsts, bdeg, E, B);
    bucket_prefix_kernel<<<1, BMAX, 0, stream>>>(bdeg, bbase, bcur, B);
    binning_kernel<<<(E + TILE - 1) / TILE, 256, 0, stream>>>(srcs, dsts, bcur,
                                                              staging, E, B);
    finalize_kernel<<<B, 256, 0, stream>>>(staging, bdeg, bbase, csr, deg, start,
                                           dinv, n);
    build_m_kernel<<<dim3(65, 2), 256, 0, stream>>>(Wz, bz, Wh, bh, Lzw, Lzb, Lhw,
                                                    Lhb, Mz, cz, Mh, ch);
    gather_kernel<<<(n + 3) / 4, 256, 0, stream>>>(csr, start, deg, x, dinv, agg, n);
    node_kernel<<<2048, 256, 0, stream>>>(agg, Mz, cz, Mh, ch, Wo, bo, out, n);
}